// Round 7
// baseline (286.081 us; speedup 1.0000x reference)
//
#include <hip/hip_runtime.h>
#include <hip/hip_cooperative_groups.h>
#include <stdint.h>

namespace cg = cooperative_groups;

// GMNConv R7: cooperative fused kernel (512 blocks, 2/CU) with R5 fallback.
// Phases: P0 zero/prep/cast | P1 hist | P2 scan||transpose | P3 PQ-GEMM+scatter
//         P4 gather | P5 msg-GEMM||attention | P6 H1 | P7 H2 | P8 out

typedef unsigned short u16;
typedef __bf16 bf16x8 __attribute__((ext_vector_type(8)));
typedef float f32x4 __attribute__((ext_vector_type(4)));

#define NN 8192
#define DD 128
#define EE 131072
#define GS 128

__device__ __forceinline__ float bf2f(u16 u){
  return __uint_as_float(((uint32_t)u) << 16);
}
__device__ __forceinline__ u16 f2bf(float f){
  uint32_t x = __float_as_uint(f);
  return (u16)((x + 0x7fffu + ((x >> 16) & 1u)) >> 16);
}
__device__ __forceinline__ void gload16(const u16* g, u16* l){
  __builtin_amdgcn_global_load_lds(
      (const __attribute__((address_space(1))) uint32_t*)(uintptr_t)g,
      (__attribute__((address_space(3))) uint32_t*)(uintptr_t)l, 16, 0, 0);
}

struct GArgs {
  const float *x1, *x2;
  const int   *ei1, *ei2;
  const float *mW1, *mb1, *mW2, *mb2;
  const float *uW1, *ub1, *uW2, *ub2, *uW3, *ub3;
  float* out;
  u16 *S, *PQ, *xb, *xt, *U, *H1, *H2;
  int *deg, *offs1, *offs2, *cur1, *cur2, *srt1, *srt2;
  u16 *WtPQ; float* bPQ;
  u16 *Wtm2, *Wtu1, *Wtu2, *Wtu3;
};

// ---- shared GEMM body: C[128x128 tile] = f(A@Wt^T + bias [+res]) ----
template<bool RELU, bool DEGBIAS, bool RES, typename OT>
__device__ __forceinline__ void gemm_body(
    const u16* __restrict__ A, int lda,
    const u16* __restrict__ Wt, const float* __restrict__ bias,
    const int* __restrict__ deg,
    const float* __restrict__ res1, const float* __restrict__ res2,
    OT* __restrict__ out, int ldc, int K, int bx, int by,
    u16* As, u16* Bs, int t)
{
  const int brow = by << 7, bcol = bx << 7;
  const int w = t >> 6, lane = t & 63;
  const int rb = (w >> 1) << 6, cb = (w & 1) << 6;
  const int lr = lane & 15, lq = lane >> 4;

  f32x4 acc[4][4];
  #pragma unroll
  for (int i = 0; i < 4; i++)
    #pragma unroll
    for (int j = 0; j < 4; j++) acc[i][j] = (f32x4){0.f, 0.f, 0.f, 0.f};

  const int s0 = t, s1 = t + 256;
  const u16* Ag0 = A  + (size_t)(brow + (s0 >> 2)) * lda + ((s0 & 3) << 3);
  const u16* Ag1 = A  + (size_t)(brow + (s1 >> 2)) * lda + ((s1 & 3) << 3);
  const u16* Bg0 = Wt + (size_t)(bcol + (s0 >> 2)) * K   + ((s0 & 3) << 3);
  const u16* Bg1 = Wt + (size_t)(bcol + (s1 >> 2)) * K   + ((s1 & 3) << 3);
  u16* Al0 = &As[s0 * 8]; u16* Al1 = &As[s1 * 8];
  u16* Bl0 = &Bs[s0 * 8]; u16* Bl1 = &Bs[s1 * 8];

  for (int kb = 0; kb < K; kb += 32){
    gload16(Ag0 + kb, Al0);
    gload16(Ag1 + kb, Al1);
    gload16(Bg0 + kb, Bl0);
    gload16(Bg1 + kb, Bl1);
    __syncthreads();
    bf16x8 af[4], bfr[4];
    #pragma unroll
    for (int mi = 0; mi < 4; mi++)
      af[mi] = *(const bf16x8*)&As[(rb + mi * 16 + lr) * 32 + (lq << 3)];
    #pragma unroll
    for (int ni = 0; ni < 4; ni++)
      bfr[ni] = *(const bf16x8*)&Bs[(cb + ni * 16 + lr) * 32 + (lq << 3)];
    #pragma unroll
    for (int mi = 0; mi < 4; mi++)
      #pragma unroll
      for (int ni = 0; ni < 4; ni++)
        acc[mi][ni] = __builtin_amdgcn_mfma_f32_16x16x32_bf16(af[mi], bfr[ni], acc[mi][ni], 0, 0, 0);
    __syncthreads();
  }

  #pragma unroll
  for (int mi = 0; mi < 4; mi++)
    #pragma unroll
    for (int ni = 0; ni < 4; ni++)
      #pragma unroll
      for (int rr = 0; rr < 4; rr++){
        int grow = brow + rb + mi * 16 + lq * 4 + rr;
        int gcol = bcol + cb + ni * 16 + lr;
        float v = acc[mi][ni][rr];
        if (bias) v += DEGBIAS ? (float)deg[grow] * bias[gcol] : bias[gcol];
        if constexpr (RELU) v = fmaxf(v, 0.f);
        if constexpr (RES){
          const float* rp = (grow < NN) ? res1 : res2;
          v += rp[(size_t)(grow & (NN - 1)) * ldc + gcol];
        }
        if constexpr (sizeof(OT) == 2) out[(size_t)grow * ldc + gcol] = (OT)f2bf(v);
        else                           out[(size_t)grow * ldc + gcol] = (OT)v;
      }
}

// ---- phase bodies (shared by fused + fallback) ----
__device__ __forceinline__ void prep_weights(const GArgs& p, int vb, int t){
  if (vb < 512){                       // WtPQ [1024][128]
    int idx = vb * 256 + t; int c = idx >> 7, k = idx & 127;
    int row = (c < 512) ? k : 128 + k;
    p.WtPQ[idx] = f2bf(p.mW1[(size_t)row * 512 + (c & 511)]);
  } else if (vb < 1024){               // Wtm2 [256][512]
    int idx = (vb - 512) * 256 + t; int c = idx >> 9, k = idx & 511;
    p.Wtm2[idx] = f2bf(p.mW2[(size_t)k * 256 + c]);
  } else if (vb < 2048){               // Wtu1 [512][512]
    int idx = (vb - 1024) * 256 + t; int c = idx >> 9, k = idx & 511;
    p.Wtu1[idx] = f2bf(p.uW1[(size_t)k * 512 + c]);
  } else if (vb < 2560){               // Wtu2 [256][512]
    int idx = (vb - 2048) * 256 + t; int c = idx >> 9, k = idx & 511;
    p.Wtu2[idx] = f2bf(p.uW2[(size_t)k * 256 + c]);
  } else if (vb < 2688){               // Wtu3 [128][256]
    int idx = (vb - 2560) * 256 + t; int c = idx >> 8, k = idx & 255;
    p.Wtu3[idx] = f2bf(p.uW3[(size_t)k * 128 + c]);
  } else {                             // bPQ [1024]
    int idx = (vb - 2688) * 256 + t;
    p.bPQ[idx] = (idx < 512) ? 0.f : p.mb1[idx - 512];
  }
}

__device__ __forceinline__ void cast_x_one(const GArgs& p, int a, int t){
  int side = a >> 12, blk = a & 4095;
  const float* x = side ? p.x2 : p.x1;
  int idx = blk * 256 + t;
  int n = idx >> 7, d = idx & 127;
  u16 v = f2bf(x[idx]);
  p.xb[(size_t)side * NN * DD + idx] = v;
  p.U[((size_t)side * NN + n) * 512 + 384 + d] = v;
}

__device__ __forceinline__ void hist_one(const GArgs& p, int idx, int t){
  int side = idx >> 9, blk = idx & 511;
  const int* ei = side ? p.ei2 : p.ei1;
  int e = blk * 256 + t;
  atomicAdd(&p.deg[side * NN + ei[e]], 1);
}

__device__ __forceinline__ void scatter_one(const GArgs& p, int idx, int t){
  int side = idx >> 9, blk = idx & 511;
  const int* ei = side ? p.ei2 : p.ei1;
  int* cur = side ? p.cur2 : p.cur1;
  int* srt = side ? p.srt2 : p.srt1;
  int e = blk * 256 + t;
  int tgt = ei[e], src = ei[EE + e];
  int pos = atomicAdd(&cur[tgt], 1);
  srt[pos] = src;
}

__device__ __forceinline__ void scan_one(const GArgs& p, int b, int t, int* part){
  const int* d = p.deg + b * NN;
  int* offs = b ? p.offs2 : p.offs1;
  int* cur  = b ? p.cur2  : p.cur1;
  const int base = t * 32;
  int loc[32];
  int s = 0;
  #pragma unroll
  for (int i = 0; i < 32; i++){ loc[i] = s; s += d[base + i]; }
  part[t] = s;
  __syncthreads();
  for (int off = 1; off < 256; off <<= 1){
    int v = (t >= off) ? part[t - off] : 0;
    __syncthreads();
    part[t] += v;
    __syncthreads();
  }
  int pre = (t == 0) ? 0 : part[t - 1];
  #pragma unroll
  for (int i = 0; i < 32; i++){
    int o = pre + loc[i];
    offs[base + i] = o;
    cur[base + i]  = o;
  }
  if (t == 255) offs[NN] = part[255];
}

__device__ __forceinline__ void transpose_one(const GArgs& p, int a, int t, u16* T){
  int side = a >> 7, blk = a & 127;
  const u16* src = p.xb + (size_t)side * NN * DD;
  u16* dst = p.xt + (size_t)side * DD * NN;
  const int n0 = blk * 64;
  #pragma unroll
  for (int i = 0; i < 4; i++){
    int s = i * 256 + t; int r = s >> 4, c8 = (s & 15) << 3;
    *(uint4*)&T[r * 136 + c8] = *(const uint4*)(src + (size_t)(n0 + r) * DD + c8);
  }
  __syncthreads();
  #pragma unroll
  for (int i = 0; i < 8; i++){
    int s = i * 256 + t;
    int d = s >> 4, n4 = (s & 15) << 2;
    uint32_t a0 = T[(n4 + 0) * 136 + d];
    uint32_t a1 = T[(n4 + 1) * 136 + d];
    uint32_t a2 = T[(n4 + 2) * 136 + d];
    uint32_t a3 = T[(n4 + 3) * 136 + d];
    uint2 pk; pk.x = a0 | (a1 << 16); pk.y = a2 | (a3 << 16);
    *(uint2*)(dst + (size_t)d * NN + n0 + n4) = pk;
  }
}

__device__ __forceinline__ void gather_one(const GArgs& p, int nv, int lane){
  int side = nv >> 13, node = nv & (NN - 1);
  const int* offs = side ? p.offs2 : p.offs1;
  const int* srt  = side ? p.srt2  : p.srt1;
  const u16* base = p.PQ + (size_t)side * NN * 1024;
  const int beg = offs[node], end = offs[node + 1];

  uint4 qv = *(const uint4*)(base + (size_t)node * 1024 + 512 + (lane << 3));
  float q[8];
  {
    uint32_t qw[4] = {qv.x, qv.y, qv.z, qv.w};
    #pragma unroll
    for (int i = 0; i < 4; i++){
      q[i * 2]     = bf2f((u16)(qw[i] & 0xffffu));
      q[i * 2 + 1] = bf2f((u16)(qw[i] >> 16));
    }
  }
  float acc[8] = {0.f,0.f,0.f,0.f,0.f,0.f,0.f,0.f};
  int e = beg;
  for (; e + 3 < end; e += 4){
    int sA = srt[e], sB = srt[e+1], sC = srt[e+2], sD = srt[e+3];
    uint4 pA = *(const uint4*)(base + (size_t)sA * 1024 + (lane << 3));
    uint4 pB = *(const uint4*)(base + (size_t)sB * 1024 + (lane << 3));
    uint4 pC = *(const uint4*)(base + (size_t)sC * 1024 + (lane << 3));
    uint4 pD = *(const uint4*)(base + (size_t)sD * 1024 + (lane << 3));
    uint32_t aw[4] = {pA.x, pA.y, pA.z, pA.w};
    uint32_t bw[4] = {pB.x, pB.y, pB.z, pB.w};
    uint32_t cw[4] = {pC.x, pC.y, pC.z, pC.w};
    uint32_t dw[4] = {pD.x, pD.y, pD.z, pD.w};
    #pragma unroll
    for (int i = 0; i < 4; i++){
      acc[i*2]   += fmaxf(bf2f((u16)(aw[i] & 0xffffu)) + q[i*2],   0.f)
                  + fmaxf(bf2f((u16)(bw[i] & 0xffffu)) + q[i*2],   0.f)
                  + fmaxf(bf2f((u16)(cw[i] & 0xffffu)) + q[i*2],   0.f)
                  + fmaxf(bf2f((u16)(dw[i] & 0xffffu)) + q[i*2],   0.f);
      acc[i*2+1] += fmaxf(bf2f((u16)(aw[i] >> 16))     + q[i*2+1], 0.f)
                  + fmaxf(bf2f((u16)(bw[i] >> 16))     + q[i*2+1], 0.f)
                  + fmaxf(bf2f((u16)(cw[i] >> 16))     + q[i*2+1], 0.f)
                  + fmaxf(bf2f((u16)(dw[i] >> 16))     + q[i*2+1], 0.f);
    }
  }
  for (; e < end; e++){
    int sA = srt[e];
    uint4 pA = *(const uint4*)(base + (size_t)sA * 1024 + (lane << 3));
    uint32_t aw[4] = {pA.x, pA.y, pA.z, pA.w};
    #pragma unroll
    for (int i = 0; i < 4; i++){
      acc[i*2]   += fmaxf(bf2f((u16)(aw[i] & 0xffffu)) + q[i*2],   0.f);
      acc[i*2+1] += fmaxf(bf2f((u16)(aw[i] >> 16))     + q[i*2+1], 0.f);
    }
  }
  uint4 pk;
  pk.x = (uint32_t)f2bf(acc[0]) | ((uint32_t)f2bf(acc[1]) << 16);
  pk.y = (uint32_t)f2bf(acc[2]) | ((uint32_t)f2bf(acc[3]) << 16);
  pk.z = (uint32_t)f2bf(acc[4]) | ((uint32_t)f2bf(acc[5]) << 16);
  pk.w = (uint32_t)f2bf(acc[6]) | ((uint32_t)f2bf(acc[7]) << 16);
  *(uint4*)(p.S + ((size_t)side * NN + node) * 512 + (lane << 3)) = pk;
}

// R5-verified attention block (XaS + XbS LDS staging). sh >= 26112 u16.
__device__ __forceinline__ void attn_one(const GArgs& p, int a, int t, u16* sh){
  const int side = a >> 7;
  const int g = a & 63, h = (a >> 6) & 1;
  const u16* Xa = p.xb + (size_t)side * NN * DD;
  const u16* Xb = p.xb + (size_t)(1 - side) * NN * DD;
  const u16* Xt = p.xt + (size_t)(1 - side) * DD * NN;
  u16* Uside = p.U + (size_t)side * NN * 512;
  u16* XaS = sh;            // 64*136
  u16* XbS = sh + 8704;     // 128*136

  const int w = t >> 6, lane = t & 63;
  const int lr = lane & 15, lq = lane >> 4;

  {
    const u16* sa = Xa + ((size_t)g * GS + h * 64) * DD;
    #pragma unroll
    for (int i = 0; i < 4; i++){
      int s = i * 256 + t; int r = s >> 4, c8 = (s & 15) << 3;
      *(uint4*)&XaS[r * 136 + c8] = *(const uint4*)(sa + (size_t)r * DD + c8);
    }
    const u16* sb = Xb + (size_t)g * GS * DD;
    #pragma unroll
    for (int i = 0; i < 8; i++){
      int s = i * 256 + t; int r = s >> 4, c8 = (s & 15) << 3;
      *(uint4*)&XbS[r * 136 + c8] = *(const uint4*)(sb + (size_t)r * DD + c8);
    }
  }
  __syncthreads();

  f32x4 sc[8];
  #pragma unroll
  for (int ct = 0; ct < 8; ct++) sc[ct] = (f32x4){0.f, 0.f, 0.f, 0.f};
  #pragma unroll
  for (int kb = 0; kb < 4; kb++){
    bf16x8 aa = *(const bf16x8*)&XaS[(w * 16 + lr) * 136 + kb * 32 + (lq << 3)];
    #pragma unroll
    for (int ct = 0; ct < 8; ct++){
      bf16x8 bb = *(const bf16x8*)&XbS[(ct * 16 + lr) * 136 + kb * 32 + (lq << 3)];
      sc[ct] = __builtin_amdgcn_mfma_f32_16x16x32_bf16(aa, bb, sc[ct], 0, 0, 0);
    }
  }
  float inv[4];
  #pragma unroll
  for (int rr = 0; rr < 4; rr++){
    float m = sc[0][rr];
    #pragma unroll
    for (int ct = 1; ct < 8; ct++) m = fmaxf(m, sc[ct][rr]);
    #pragma unroll
    for (int sh_ = 1; sh_ < 16; sh_ <<= 1) m = fmaxf(m, __shfl_xor(m, sh_, 64));
    float s = 0.f;
    #pragma unroll
    for (int ct = 0; ct < 8; ct++){
      float e = __expf(sc[ct][rr] - m);
      sc[ct][rr] = e; s += e;
    }
    #pragma unroll
    for (int sh_ = 1; sh_ < 16; sh_ <<= 1) s += __shfl_xor(s, sh_, 64);
    inv[rr] = 1.f / s;
  }
  #pragma unroll
  for (int ct = 0; ct < 8; ct++)
    #pragma unroll
    for (int rr = 0; rr < 4; rr++)
      XaS[(w * 16 + lq * 4 + rr) * 136 + ct * 16 + lr] = f2bf(sc[ct][rr] * inv[rr]);
  __syncthreads();

  f32x4 o[8];
  #pragma unroll
  for (int ct = 0; ct < 8; ct++) o[ct] = (f32x4){0.f, 0.f, 0.f, 0.f};
  #pragma unroll
  for (int kb = 0; kb < 4; kb++){
    bf16x8 aa = *(const bf16x8*)&XaS[(w * 16 + lr) * 136 + kb * 32 + (lq << 3)];
    #pragma unroll
    for (int ct = 0; ct < 8; ct++){
      bf16x8 bb = *(const bf16x8*)(Xt + (size_t)(ct * 16 + lr) * NN + g * GS + kb * 32 + (lq << 3));
      o[ct] = __builtin_amdgcn_mfma_f32_16x16x32_bf16(aa, bb, o[ct], 0, 0, 0);
    }
  }
  const u16* XaEp = Xa + ((size_t)g * GS + h * 64) * DD;
  #pragma unroll
  for (int ct = 0; ct < 8; ct++)
    #pragma unroll
    for (int rr = 0; rr < 4; rr++){
      int row = w * 16 + lq * 4 + rr, col = ct * 16 + lr;
      float xa = bf2f(XaEp[(size_t)row * DD + col]);
      Uside[((size_t)g * GS + h * 64 + row) * 512 + 256 + col] = f2bf(xa - o[ct][rr]);
    }
}

// ================= cooperative fused kernel: 512 blocks, 2/CU =================
__global__ __launch_bounds__(256, 2)
void fused_k(GArgs p)
{
  __shared__ u16 sh[26112];     // 52224 B (attn XaS+XbS; gemm uses first 16 KB)
  __shared__ int part[256];
  const int b = blockIdx.x, t = threadIdx.x;
  const int w = t >> 6, lane = t & 63;
  cg::grid_group grid = cg::this_grid();

  // P0: zero deg | weight prep | cast x
  {
    int gid = b * 256 + t;
    if (gid < 2 * NN) p.deg[gid] = 0;
    for (int vb = b; vb < 2692; vb += 512) prep_weights(p, vb, t);
    for (int a = b; a < 8192; a += 512) cast_x_one(p, a, t);
  }
  grid.sync();

  // P1: histogram
  #pragma unroll
  for (int r = 0; r < 2; r++) hist_one(p, r * 512 + b, t);
  grid.sync();

  // P2: scan (blocks 0,1) || transpose (blocks 2..257)
  if (b < 2) scan_one(p, b, t, part);
  else if (b < 258) transpose_one(p, b - 2, t, sh);
  grid.sync();

  // P3: PQ GEMM (1024 tiles over 512 blocks) + scatter
  #pragma unroll
  for (int r = 0; r < 2; r++){
    int tile = r * 512 + b;
    gemm_body<false,false,false,u16>(p.xb, 128, p.WtPQ, p.bPQ, nullptr, nullptr, nullptr,
                                     p.PQ, 1024, 128, tile & 7, tile >> 3,
                                     sh, sh + 4096, t);
  }
  #pragma unroll
  for (int r = 0; r < 2; r++) scatter_one(p, r * 512 + b, t);
  grid.sync();

  // P4: gather (16384 node-waves over 512 blocks x 4 waves)
  #pragma unroll
  for (int it = 0; it < 8; it++) gather_one(p, it * 2048 + b * 4 + w, lane);
  grid.sync();

  // P5: msg GEMM (0..255) || attention (256..511)
  if (b < 256)
    gemm_body<false,true,false,u16>(p.S, 512, p.Wtm2, p.mb2, p.deg, nullptr, nullptr,
                                    p.U, 512, 512, b & 1, b >> 1, sh, sh + 4096, t);
  else
    attn_one(p, b - 256, t, sh);
  grid.sync();

  // P6: H1 = relu(U@uW1+b1)  (512 tiles)
  gemm_body<true,false,false,u16>(p.U, 512, p.Wtu1, p.ub1, nullptr, nullptr, nullptr,
                                  p.H1, 512, 512, b & 3, b >> 2, sh, sh + 4096, t);
  grid.sync();

  // P7: H2 = relu(H1@uW2+b2)  (256 tiles)
  if (b < 256)
    gemm_body<true,false,false,u16>(p.H1, 512, p.Wtu2, p.ub2, nullptr, nullptr, nullptr,
                                    p.H2, 256, 512, b & 1, b >> 1, sh, sh + 4096, t);
  grid.sync();

  // P8: out = x + H2@uW3+b3  (128 tiles)
  if (b < 128)
    gemm_body<false,false,true,float>(p.H2, 256, p.Wtu3, p.ub3, nullptr, p.x1, p.x2,
                                      p.out, 128, 256, 0, b, sh, sh + 4096, t);
}

// ================= fallback kernels (R5 pipeline, verified) =================
__global__ __launch_bounds__(256)
void pre_k(GArgs p){
  int b = blockIdx.x, t = threadIdx.x;
  if (b < 2692) prep_weights(p, b, t);
  else if (b < 2692 + 8192) cast_x_one(p, b - 2692, t);
  else hist_one(p, b - (2692 + 8192), t);
}

__global__ __launch_bounds__(256)
void scan_k(GArgs p){
  __shared__ int part[256];
  scan_one(p, blockIdx.x, threadIdx.x, part);
}

__global__ __launch_bounds__(256)
void mid_k(GArgs p){
  __shared__ u16 sh[8704];
  int b = blockIdx.x, t = threadIdx.x;
  if (b < 1024)
    gemm_body<false,false,false,u16>(p.xb, 128, p.WtPQ, p.bPQ, nullptr, nullptr, nullptr,
                                     p.PQ, 1024, 128, b & 7, b >> 3, sh, sh + 4096, t);
  else if (b < 2048) scatter_one(p, b - 1024, t);
  else transpose_one(p, b - 2048, t, sh);
}

__global__ __launch_bounds__(256)
void gather_k(GArgs p){
  gather_one(p, blockIdx.y * NN + blockIdx.x * 4 + (threadIdx.x >> 6),
             threadIdx.x & 63);
}

__global__ __launch_bounds__(256)
void msgattn_k(GArgs p){
  __shared__ u16 sh[26112];
  int b = blockIdx.x, t = threadIdx.x;
  if (b < 256)
    gemm_body<false,true,false,u16>(p.S, 512, p.Wtm2, p.mb2, p.deg, nullptr, nullptr,
                                    p.U, 512, 512, b & 1, b >> 1, sh, sh + 4096, t);
  else
    attn_one(p, b - 256, t, sh);
}

__global__ __launch_bounds__(256)
void h1_k(GArgs p){
  __shared__ u16 sh[8192];
  gemm_body<true,false,false,u16>(p.U, 512, p.Wtu1, p.ub1, nullptr, nullptr, nullptr,
                                  p.H1, 512, 512, blockIdx.x, blockIdx.y,
                                  sh, sh + 4096, threadIdx.x);
}
__global__ __launch_bounds__(256)
void h2_k(GArgs p){
  __shared__ u16 sh[8192];
  gemm_body<true,false,false,u16>(p.H1, 512, p.Wtu2, p.ub2, nullptr, nullptr, nullptr,
                                  p.H2, 256, 512, blockIdx.x, blockIdx.y,
                                  sh, sh + 4096, threadIdx.x);
}
__global__ __launch_bounds__(256)
void out_k(GArgs p){
  __shared__ u16 sh[8192];
  gemm_body<false,false,true,float>(p.H2, 256, p.Wtu3, p.ub3, nullptr, p.x1, p.x2,
                                    p.out, 128, 256, blockIdx.x, blockIdx.y,
                                    sh, sh + 4096, threadIdx.x);
}

extern "C" void kernel_launch(void* const* d_in, const int* in_sizes, int n_in,
                              void* d_out, int out_size, void* d_ws, size_t ws_size,
                              hipStream_t stream)
{
  GArgs a;
  a.x1  = (const float*)d_in[0];
  a.ei1 = (const int*)  d_in[1];
  a.x2  = (const float*)d_in[3];
  a.ei2 = (const int*)  d_in[4];
  a.mW1 = (const float*)d_in[6];
  a.mb1 = (const float*)d_in[7];
  a.mW2 = (const float*)d_in[8];
  a.mb2 = (const float*)d_in[9];
  a.uW1 = (const float*)d_in[10];
  a.ub1 = (const float*)d_in[11];
  a.uW2 = (const float*)d_in[12];
  a.ub2 = (const float*)d_in[13];
  a.uW3 = (const float*)d_in[14];
  a.ub3 = (const float*)d_in[15];
  a.out = (float*)d_out;

  char* w = (char*)d_ws;
  auto alloc = [&](size_t b){ char* p = w; w += (b + 255) & ~(size_t)255; return p; };
  a.S    = (u16*)alloc((size_t)2 * NN * 512 * 2);
  a.PQ   = (u16*)alloc((size_t)2 * NN * 1024 * 2);
  a.xb   = (u16*)alloc((size_t)2 * NN * DD * 2);
  a.xt   = (u16*)alloc((size_t)2 * DD * NN * 2);
  a.U    = (u16*)alloc((size_t)2 * NN * 512 * 2);
  a.H1   = (u16*)alloc((size_t)2 * NN * 512 * 2);
  a.H2   = (u16*)alloc((size_t)2 * NN * 256 * 2);
  a.deg  = (int*)alloc((size_t)2 * NN * 4);
  a.offs1 = (int*)alloc((NN + 1) * 4);
  a.offs2 = (int*)alloc((NN + 1) * 4);
  a.cur1  = (int*)alloc(NN * 4);
  a.cur2  = (int*)alloc(NN * 4);
  a.srt1  = (int*)alloc((size_t)EE * 4);
  a.srt2  = (int*)alloc((size_t)EE * 4);
  a.WtPQ = (u16*)alloc(1024 * 128 * 2);
  a.bPQ  = (float*)alloc(1024 * 4);
  a.Wtm2 = (u16*)alloc(256 * 512 * 2);
  a.Wtu1 = (u16*)alloc(512 * 512 * 2);
  a.Wtu2 = (u16*)alloc(256 * 512 * 2);
  a.Wtu3 = (u16*)alloc(128 * 256 * 2);

  // capture-safe occupancy gate for the cooperative path
  int maxB = 0;
  hipError_t qe = hipOccupancyMaxActiveBlocksPerMultiprocessor(&maxB, fused_k, 256, 0);
  if (qe == hipSuccess && maxB >= 2){
    void* kargs[] = { (void*)&a };
    if (hipLaunchCooperativeKernel((const void*)fused_k, dim3(512), dim3(256),
                                   kargs, 0, stream) == hipSuccess)
      return;
  }

  // fallback: R5 pipeline
  hipMemsetAsync(a.deg, 0, (size_t)2 * NN * 4, stream);
  pre_k<<<2692 + 8192 + 1024, 256, 0, stream>>>(a);
  scan_k<<<2, 256, 0, stream>>>(a);
  mid_k<<<2304, 256, 0, stream>>>(a);
  gather_k<<<dim3(2048, 2), 256, 0, stream>>>(a);
  msgattn_k<<<512, 256, 0, stream>>>(a);
  h1_k<<<dim3(4, 128), 256, 0, stream>>>(a);
  h2_k<<<dim3(2, 128), 256, 0, stream>>>(a);
  out_k<<<dim3(1, 128), 256, 0, stream>>>(a);
}

// Round 8
// 285.841 us; speedup vs baseline: 1.0008x; 1.0008x over previous
//
#include <hip/hip_runtime.h>
#include <hip/hip_cooperative_groups.h>
#include <stdint.h>

namespace cg = cooperative_groups;

// GMNConv R8: cooperative fused kernel, 3 grid.syncs + flag-chained DAG phase.
//  P0: zero deg/flags | weight prep | cast x
//  P1: hist || transpose || PQ GEMM
//  P2: scan (2 blocks) --scanDone--> scatter
//  P3: gather --chunkDone--> msg || attn --uRow--> H1 --h1Row--> H2 --h2Row--> out
// Fallback: R5 multi-kernel pipeline (gated on occupancy/launch failure).

typedef unsigned short u16;
typedef __bf16 bf16x8 __attribute__((ext_vector_type(8)));
typedef float f32x4 __attribute__((ext_vector_type(4)));

#define NN 8192
#define DD 128
#define EE 131072
#define GS 128

__device__ __forceinline__ float bf2f(u16 u){
  return __uint_as_float(((uint32_t)u) << 16);
}
__device__ __forceinline__ u16 f2bf(float f){
  uint32_t x = __float_as_uint(f);
  return (u16)((x + 0x7fffu + ((x >> 16) & 1u)) >> 16);
}
__device__ __forceinline__ void gload16(const u16* g, u16* l){
  __builtin_amdgcn_global_load_lds(
      (const __attribute__((address_space(1))) uint32_t*)(uintptr_t)g,
      (__attribute__((address_space(3))) uint32_t*)(uintptr_t)l, 16, 0, 0);
}
__device__ __forceinline__ void spin_until(int* f, int target){
  while (__hip_atomic_load(f, __ATOMIC_ACQUIRE, __HIP_MEMORY_SCOPE_AGENT) < target)
    __builtin_amdgcn_s_sleep(8);
}
__device__ __forceinline__ void signal_add(int* f){
  __hip_atomic_fetch_add(f, 1, __ATOMIC_RELEASE, __HIP_MEMORY_SCOPE_AGENT);
}

struct GArgs {
  const float *x1, *x2;
  const int   *ei1, *ei2;
  const float *mW1, *mb1, *mW2, *mb2;
  const float *uW1, *ub1, *uW2, *ub2, *uW3, *ub3;
  float* out;
  u16 *S, *PQ, *xb, *xt, *U, *H1, *H2;
  int *deg, *offs1, *offs2, *cur1, *cur2, *srt1, *srt2;
  int *flags;                       // [0] scanDone; [8..136) uRow; [136..264) h1Row;
                                    // [264..392) h2Row; [392..520) chunkDone
  u16 *WtPQ; float* bPQ;
  u16 *Wtm2, *Wtu1, *Wtu2, *Wtu3;
};

// ---- shared GEMM body: C[128x128 tile] = f(A@Wt^T + bias [+res]) ----
template<bool RELU, bool DEGBIAS, bool RES, typename OT>
__device__ __forceinline__ void gemm_body(
    const u16* __restrict__ A, int lda,
    const u16* __restrict__ Wt, const float* __restrict__ bias,
    const int* __restrict__ deg,
    const float* __restrict__ res1, const float* __restrict__ res2,
    OT* __restrict__ out, int ldc, int K, int bx, int by,
    u16* As, u16* Bs, int t)
{
  const int brow = by << 7, bcol = bx << 7;
  const int w = t >> 6, lane = t & 63;
  const int rb = (w >> 1) << 6, cb = (w & 1) << 6;
  const int lr = lane & 15, lq = lane >> 4;

  f32x4 acc[4][4];
  #pragma unroll
  for (int i = 0; i < 4; i++)
    #pragma unroll
    for (int j = 0; j < 4; j++) acc[i][j] = (f32x4){0.f, 0.f, 0.f, 0.f};

  const int s0 = t, s1 = t + 256;
  const u16* Ag0 = A  + (size_t)(brow + (s0 >> 2)) * lda + ((s0 & 3) << 3);
  const u16* Ag1 = A  + (size_t)(brow + (s1 >> 2)) * lda + ((s1 & 3) << 3);
  const u16* Bg0 = Wt + (size_t)(bcol + (s0 >> 2)) * K   + ((s0 & 3) << 3);
  const u16* Bg1 = Wt + (size_t)(bcol + (s1 >> 2)) * K   + ((s1 & 3) << 3);
  u16* Al0 = &As[s0 * 8]; u16* Al1 = &As[s1 * 8];
  u16* Bl0 = &Bs[s0 * 8]; u16* Bl1 = &Bs[s1 * 8];

  for (int kb = 0; kb < K; kb += 32){
    gload16(Ag0 + kb, Al0);
    gload16(Ag1 + kb, Al1);
    gload16(Bg0 + kb, Bl0);
    gload16(Bg1 + kb, Bl1);
    __syncthreads();
    bf16x8 af[4], bfr[4];
    #pragma unroll
    for (int mi = 0; mi < 4; mi++)
      af[mi] = *(const bf16x8*)&As[(rb + mi * 16 + lr) * 32 + (lq << 3)];
    #pragma unroll
    for (int ni = 0; ni < 4; ni++)
      bfr[ni] = *(const bf16x8*)&Bs[(cb + ni * 16 + lr) * 32 + (lq << 3)];
    #pragma unroll
    for (int mi = 0; mi < 4; mi++)
      #pragma unroll
      for (int ni = 0; ni < 4; ni++)
        acc[mi][ni] = __builtin_amdgcn_mfma_f32_16x16x32_bf16(af[mi], bfr[ni], acc[mi][ni], 0, 0, 0);
    __syncthreads();
  }

  #pragma unroll
  for (int mi = 0; mi < 4; mi++)
    #pragma unroll
    for (int ni = 0; ni < 4; ni++)
      #pragma unroll
      for (int rr = 0; rr < 4; rr++){
        int grow = brow + rb + mi * 16 + lq * 4 + rr;
        int gcol = bcol + cb + ni * 16 + lr;
        float v = acc[mi][ni][rr];
        if (bias) v += DEGBIAS ? (float)deg[grow] * bias[gcol] : bias[gcol];
        if constexpr (RELU) v = fmaxf(v, 0.f);
        if constexpr (RES){
          const float* rp = (grow < NN) ? res1 : res2;
          v += rp[(size_t)(grow & (NN - 1)) * ldc + gcol];
        }
        if constexpr (sizeof(OT) == 2) out[(size_t)grow * ldc + gcol] = (OT)f2bf(v);
        else                           out[(size_t)grow * ldc + gcol] = (OT)v;
      }
}

// ---- phase bodies (shared by fused + fallback) ----
__device__ __forceinline__ void prep_weights(const GArgs& p, int vb, int t){
  if (vb < 512){                       // WtPQ [1024][128]
    int idx = vb * 256 + t; int c = idx >> 7, k = idx & 127;
    int row = (c < 512) ? k : 128 + k;
    p.WtPQ[idx] = f2bf(p.mW1[(size_t)row * 512 + (c & 511)]);
  } else if (vb < 1024){               // Wtm2 [256][512]
    int idx = (vb - 512) * 256 + t; int c = idx >> 9, k = idx & 511;
    p.Wtm2[idx] = f2bf(p.mW2[(size_t)k * 256 + c]);
  } else if (vb < 2048){               // Wtu1 [512][512]
    int idx = (vb - 1024) * 256 + t; int c = idx >> 9, k = idx & 511;
    p.Wtu1[idx] = f2bf(p.uW1[(size_t)k * 512 + c]);
  } else if (vb < 2560){               // Wtu2 [256][512]
    int idx = (vb - 2048) * 256 + t; int c = idx >> 9, k = idx & 511;
    p.Wtu2[idx] = f2bf(p.uW2[(size_t)k * 256 + c]);
  } else if (vb < 2688){               // Wtu3 [128][256]
    int idx = (vb - 2560) * 256 + t; int c = idx >> 8, k = idx & 255;
    p.Wtu3[idx] = f2bf(p.uW3[(size_t)k * 128 + c]);
  } else {                             // bPQ [1024]
    int idx = (vb - 2688) * 256 + t;
    p.bPQ[idx] = (idx < 512) ? 0.f : p.mb1[idx - 512];
  }
}

__device__ __forceinline__ void cast_x_one(const GArgs& p, int a, int t){
  int side = a >> 12, blk = a & 4095;
  const float* x = side ? p.x2 : p.x1;
  int idx = blk * 256 + t;
  int n = idx >> 7, d = idx & 127;
  u16 v = f2bf(x[idx]);
  p.xb[(size_t)side * NN * DD + idx] = v;
  p.U[((size_t)side * NN + n) * 512 + 384 + d] = v;
}

__device__ __forceinline__ void hist_one(const GArgs& p, int idx, int t){
  int side = idx >> 9, blk = idx & 511;
  const int* ei = side ? p.ei2 : p.ei1;
  int e = blk * 256 + t;
  atomicAdd(&p.deg[side * NN + ei[e]], 1);
}

__device__ __forceinline__ void scatter_one(const GArgs& p, int idx, int t){
  int side = idx >> 9, blk = idx & 511;
  const int* ei = side ? p.ei2 : p.ei1;
  int* cur = side ? p.cur2 : p.cur1;
  int* srt = side ? p.srt2 : p.srt1;
  int e = blk * 256 + t;
  int tgt = ei[e], src = ei[EE + e];
  int pos = atomicAdd(&cur[tgt], 1);
  srt[pos] = src;
}

__device__ __forceinline__ void scan_one(const GArgs& p, int b, int t, int* part){
  const int* d = p.deg + b * NN;
  int* offs = b ? p.offs2 : p.offs1;
  int* cur  = b ? p.cur2  : p.cur1;
  const int base = t * 32;
  int loc[32];
  int s = 0;
  #pragma unroll
  for (int i = 0; i < 32; i++){ loc[i] = s; s += d[base + i]; }
  part[t] = s;
  __syncthreads();
  for (int off = 1; off < 256; off <<= 1){
    int v = (t >= off) ? part[t - off] : 0;
    __syncthreads();
    part[t] += v;
    __syncthreads();
  }
  int pre = (t == 0) ? 0 : part[t - 1];
  #pragma unroll
  for (int i = 0; i < 32; i++){
    int o = pre + loc[i];
    offs[base + i] = o;
    cur[base + i]  = o;
  }
  if (t == 255) offs[NN] = part[255];
}

__device__ __forceinline__ void transpose_one(const GArgs& p, int a, int t, u16* T){
  int side = a >> 7, blk = a & 127;
  const u16* src = p.xb + (size_t)side * NN * DD;
  u16* dst = p.xt + (size_t)side * DD * NN;
  const int n0 = blk * 64;
  #pragma unroll
  for (int i = 0; i < 4; i++){
    int s = i * 256 + t; int r = s >> 4, c8 = (s & 15) << 3;
    *(uint4*)&T[r * 136 + c8] = *(const uint4*)(src + (size_t)(n0 + r) * DD + c8);
  }
  __syncthreads();
  #pragma unroll
  for (int i = 0; i < 8; i++){
    int s = i * 256 + t;
    int d = s >> 4, n4 = (s & 15) << 2;
    uint32_t a0 = T[(n4 + 0) * 136 + d];
    uint32_t a1 = T[(n4 + 1) * 136 + d];
    uint32_t a2 = T[(n4 + 2) * 136 + d];
    uint32_t a3 = T[(n4 + 3) * 136 + d];
    uint2 pk; pk.x = a0 | (a1 << 16); pk.y = a2 | (a3 << 16);
    *(uint2*)(dst + (size_t)d * NN + n0 + n4) = pk;
  }
}

__device__ __forceinline__ void gather_one(const GArgs& p, int nv, int lane){
  int side = nv >> 13, node = nv & (NN - 1);
  const int* offs = side ? p.offs2 : p.offs1;
  const int* srt  = side ? p.srt2  : p.srt1;
  const u16* base = p.PQ + (size_t)side * NN * 1024;
  const int beg = offs[node], end = offs[node + 1];

  uint4 qv = *(const uint4*)(base + (size_t)node * 1024 + 512 + (lane << 3));
  float q[8];
  {
    uint32_t qw[4] = {qv.x, qv.y, qv.z, qv.w};
    #pragma unroll
    for (int i = 0; i < 4; i++){
      q[i * 2]     = bf2f((u16)(qw[i] & 0xffffu));
      q[i * 2 + 1] = bf2f((u16)(qw[i] >> 16));
    }
  }
  float acc[8] = {0.f,0.f,0.f,0.f,0.f,0.f,0.f,0.f};
  int e = beg;
  for (; e + 3 < end; e += 4){
    int sA = srt[e], sB = srt[e+1], sC = srt[e+2], sD = srt[e+3];
    uint4 pA = *(const uint4*)(base + (size_t)sA * 1024 + (lane << 3));
    uint4 pB = *(const uint4*)(base + (size_t)sB * 1024 + (lane << 3));
    uint4 pC = *(const uint4*)(base + (size_t)sC * 1024 + (lane << 3));
    uint4 pD = *(const uint4*)(base + (size_t)sD * 1024 + (lane << 3));
    uint32_t aw[4] = {pA.x, pA.y, pA.z, pA.w};
    uint32_t bw[4] = {pB.x, pB.y, pB.z, pB.w};
    uint32_t cw[4] = {pC.x, pC.y, pC.z, pC.w};
    uint32_t dw[4] = {pD.x, pD.y, pD.z, pD.w};
    #pragma unroll
    for (int i = 0; i < 4; i++){
      acc[i*2]   += fmaxf(bf2f((u16)(aw[i] & 0xffffu)) + q[i*2],   0.f)
                  + fmaxf(bf2f((u16)(bw[i] & 0xffffu)) + q[i*2],   0.f)
                  + fmaxf(bf2f((u16)(cw[i] & 0xffffu)) + q[i*2],   0.f)
                  + fmaxf(bf2f((u16)(dw[i] & 0xffffu)) + q[i*2],   0.f);
      acc[i*2+1] += fmaxf(bf2f((u16)(aw[i] >> 16))     + q[i*2+1], 0.f)
                  + fmaxf(bf2f((u16)(bw[i] >> 16))     + q[i*2+1], 0.f)
                  + fmaxf(bf2f((u16)(cw[i] >> 16))     + q[i*2+1], 0.f)
                  + fmaxf(bf2f((u16)(dw[i] >> 16))     + q[i*2+1], 0.f);
    }
  }
  for (; e < end; e++){
    int sA = srt[e];
    uint4 pA = *(const uint4*)(base + (size_t)sA * 1024 + (lane << 3));
    uint32_t aw[4] = {pA.x, pA.y, pA.z, pA.w};
    #pragma unroll
    for (int i = 0; i < 4; i++){
      acc[i*2]   += fmaxf(bf2f((u16)(aw[i] & 0xffffu)) + q[i*2],   0.f);
      acc[i*2+1] += fmaxf(bf2f((u16)(aw[i] >> 16))     + q[i*2+1], 0.f);
    }
  }
  uint4 pk;
  pk.x = (uint32_t)f2bf(acc[0]) | ((uint32_t)f2bf(acc[1]) << 16);
  pk.y = (uint32_t)f2bf(acc[2]) | ((uint32_t)f2bf(acc[3]) << 16);
  pk.z = (uint32_t)f2bf(acc[4]) | ((uint32_t)f2bf(acc[5]) << 16);
  pk.w = (uint32_t)f2bf(acc[6]) | ((uint32_t)f2bf(acc[7]) << 16);
  *(uint4*)(p.S + ((size_t)side * NN + node) * 512 + (lane << 3)) = pk;
}

// attention block (XaS + XbS LDS staging). sh >= 26112 u16.
__device__ __forceinline__ void attn_one(const GArgs& p, int a, int t, u16* sh){
  const int side = a >> 7;
  const int g = a & 63, h = (a >> 6) & 1;
  const u16* Xa = p.xb + (size_t)side * NN * DD;
  const u16* Xb = p.xb + (size_t)(1 - side) * NN * DD;
  const u16* Xt = p.xt + (size_t)(1 - side) * DD * NN;
  u16* Uside = p.U + (size_t)side * NN * 512;
  u16* XaS = sh;            // 64*136
  u16* XbS = sh + 8704;     // 128*136

  const int w = t >> 6, lane = t & 63;
  const int lr = lane & 15, lq = lane >> 4;

  {
    const u16* sa = Xa + ((size_t)g * GS + h * 64) * DD;
    #pragma unroll
    for (int i = 0; i < 4; i++){
      int s = i * 256 + t; int r = s >> 4, c8 = (s & 15) << 3;
      *(uint4*)&XaS[r * 136 + c8] = *(const uint4*)(sa + (size_t)r * DD + c8);
    }
    const u16* sb = Xb + (size_t)g * GS * DD;
    #pragma unroll
    for (int i = 0; i < 8; i++){
      int s = i * 256 + t; int r = s >> 4, c8 = (s & 15) << 3;
      *(uint4*)&XbS[r * 136 + c8] = *(const uint4*)(sb + (size_t)r * DD + c8);
    }
  }
  __syncthreads();

  f32x4 sc[8];
  #pragma unroll
  for (int ct = 0; ct < 8; ct++) sc[ct] = (f32x4){0.f, 0.f, 0.f, 0.f};
  #pragma unroll
  for (int kb = 0; kb < 4; kb++){
    bf16x8 aa = *(const bf16x8*)&XaS[(w * 16 + lr) * 136 + kb * 32 + (lq << 3)];
    #pragma unroll
    for (int ct = 0; ct < 8; ct++){
      bf16x8 bb = *(const bf16x8*)&XbS[(ct * 16 + lr) * 136 + kb * 32 + (lq << 3)];
      sc[ct] = __builtin_amdgcn_mfma_f32_16x16x32_bf16(aa, bb, sc[ct], 0, 0, 0);
    }
  }
  float inv[4];
  #pragma unroll
  for (int rr = 0; rr < 4; rr++){
    float m = sc[0][rr];
    #pragma unroll
    for (int ct = 1; ct < 8; ct++) m = fmaxf(m, sc[ct][rr]);
    #pragma unroll
    for (int sh_ = 1; sh_ < 16; sh_ <<= 1) m = fmaxf(m, __shfl_xor(m, sh_, 64));
    float s = 0.f;
    #pragma unroll
    for (int ct = 0; ct < 8; ct++){
      float e = __expf(sc[ct][rr] - m);
      sc[ct][rr] = e; s += e;
    }
    #pragma unroll
    for (int sh_ = 1; sh_ < 16; sh_ <<= 1) s += __shfl_xor(s, sh_, 64);
    inv[rr] = 1.f / s;
  }
  #pragma unroll
  for (int ct = 0; ct < 8; ct++)
    #pragma unroll
    for (int rr = 0; rr < 4; rr++)
      XaS[(w * 16 + lq * 4 + rr) * 136 + ct * 16 + lr] = f2bf(sc[ct][rr] * inv[rr]);
  __syncthreads();

  f32x4 o[8];
  #pragma unroll
  for (int ct = 0; ct < 8; ct++) o[ct] = (f32x4){0.f, 0.f, 0.f, 0.f};
  #pragma unroll
  for (int kb = 0; kb < 4; kb++){
    bf16x8 aa = *(const bf16x8*)&XaS[(w * 16 + lr) * 136 + kb * 32 + (lq << 3)];
    #pragma unroll
    for (int ct = 0; ct < 8; ct++){
      bf16x8 bb = *(const bf16x8*)(Xt + (size_t)(ct * 16 + lr) * NN + g * GS + kb * 32 + (lq << 3));
      o[ct] = __builtin_amdgcn_mfma_f32_16x16x32_bf16(aa, bb, o[ct], 0, 0, 0);
    }
  }
  const u16* XaEp = Xa + ((size_t)g * GS + h * 64) * DD;
  #pragma unroll
  for (int ct = 0; ct < 8; ct++)
    #pragma unroll
    for (int rr = 0; rr < 4; rr++){
      int row = w * 16 + lq * 4 + rr, col = ct * 16 + lr;
      float xa = bf2f(XaEp[(size_t)row * DD + col]);
      Uside[((size_t)g * GS + h * 64 + row) * 512 + 256 + col] = f2bf(xa - o[ct][rr]);
    }
}

// ================= cooperative fused kernel: 512 blocks, 2/CU =================
__global__ __launch_bounds__(256, 2)
void fused_k(GArgs p)
{
  __shared__ u16 sh[26112];     // 52 KB (attn XaS+XbS; gemm/transpose use prefix)
  __shared__ int part[256];
  const int b = blockIdx.x, t = threadIdx.x;
  const int w = t >> 6, lane = t & 63;
  cg::grid_group grid = cg::this_grid();
  int* scanDone  = p.flags;          // target 2
  int* uRow      = p.flags + 8;      // [128] target 4 (2 msg + 2 attn)
  int* h1Row     = p.flags + 136;    // [128] target 4
  int* h2Row     = p.flags + 264;    // [128] target 2
  int* chunkDone = p.flags + 392;    // [128] target 128 (one per node-wave)

  // P0: zero deg+flags | weight prep | cast x
  {
    int gid = b * 256 + t;
    if (gid < 2 * NN) p.deg[gid] = 0;
    if (gid < 520) p.flags[gid] = 0;
    for (int vb = b; vb < 2692; vb += 512) prep_weights(p, vb, t);
    for (int a = b; a < 8192; a += 512) cast_x_one(p, a, t);
  }
  grid.sync();

  // P1: hist || transpose || PQ GEMM
  hist_one(p, 2 * b, t);
  hist_one(p, 2 * b + 1, t);
  if (b < 256) transpose_one(p, b, t, sh);
  __syncthreads();                 // transpose's sh reads done before gemm reuse
  #pragma unroll 1
  for (int r = 0; r < 2; r++){
    int tile = r * 512 + b;
    gemm_body<false,false,false,u16>(p.xb, 128, p.WtPQ, p.bPQ, nullptr, nullptr, nullptr,
                                     p.PQ, 1024, 128, tile & 7, tile >> 3,
                                     sh, sh + 4096, t);
  }
  grid.sync();

  // P2: scan (blocks 0,1) --scanDone--> scatter (all blocks)
  if (b < 2){
    scan_one(p, b, t, part);
    __syncthreads();
    if (t == 0) signal_add(scanDone);
  }
  if (t == 0) spin_until(scanDone, 2);
  __syncthreads();
  scatter_one(p, 2 * b, t);
  scatter_one(p, 2 * b + 1, t);
  grid.sync();

  // P3: gather -> (msg || attn) -> H1 -> H2 -> out, flag-chained
  #pragma unroll 1
  for (int it = 0; it < 8; it++){
    int nv = it * 2048 + b * 4 + w;         // S row index == nv
    gather_one(p, nv, lane);
    if (lane == 0) signal_add(&chunkDone[nv >> 7]);
  }

  if (b < 256){
    int rt = b >> 1;
    if (t == 0) spin_until(&chunkDone[rt], 128);
    __syncthreads();
    gemm_body<false,true,false,u16>(p.S, 512, p.Wtm2, p.mb2, p.deg, nullptr, nullptr,
                                    p.U, 512, 512, b & 1, rt, sh, sh + 4096, t);
    __syncthreads();
    if (t == 0) signal_add(&uRow[rt]);
  } else {
    int a2 = b - 256;
    attn_one(p, a2, t, sh);
    __syncthreads();
    int rt = ((a2 >> 7) << 6) + (a2 & 63);  // side*64 + g
    if (t == 0) signal_add(&uRow[rt]);
  }

  {  // H1: tile b of 512
    int rt = b >> 2;
    if (t == 0) spin_until(&uRow[rt], 4);
    __syncthreads();
    gemm_body<true,false,false,u16>(p.U, 512, p.Wtu1, p.ub1, nullptr, nullptr, nullptr,
                                    p.H1, 512, 512, b & 3, rt, sh, sh + 4096, t);
    __syncthreads();
    if (t == 0) signal_add(&h1Row[rt]);
  }
  if (b < 256){  // H2: tile b of 256
    int rt = b >> 1;
    if (t == 0) spin_until(&h1Row[rt], 4);
    __syncthreads();
    gemm_body<true,false,false,u16>(p.H1, 512, p.Wtu2, p.ub2, nullptr, nullptr, nullptr,
                                    p.H2, 256, 512, b & 1, rt, sh, sh + 4096, t);
    __syncthreads();
    if (t == 0) signal_add(&h2Row[rt]);
  }
  if (b < 128){  // out: tile b of 128
    if (t == 0) spin_until(&h2Row[b], 2);
    __syncthreads();
    gemm_body<false,false,true,float>(p.H2, 256, p.Wtu3, p.ub3, nullptr, p.x1, p.x2,
                                      p.out, 128, 256, 0, b, sh, sh + 4096, t);
  }
}

// ================= fallback kernels (R5 pipeline, verified) =================
__global__ __launch_bounds__(256)
void pre_k(GArgs p){
  int b = blockIdx.x, t = threadIdx.x;
  if (b < 2692) prep_weights(p, b, t);
  else if (b < 2692 + 8192) cast_x_one(p, b - 2692, t);
  else hist_one(p, b - (2692 + 8192), t);
}

__global__ __launch_bounds__(256)
void scan_k(GArgs p){
  __shared__ int part[256];
  scan_one(p, blockIdx.x, threadIdx.x, part);
}

__global__ __launch_bounds__(256)
void mid_k(GArgs p){
  __shared__ u16 sh[8704];
  int b = blockIdx.x, t = threadIdx.x;
  if (b < 1024)
    gemm_body<false,false,false,u16>(p.xb, 128, p.WtPQ, p.bPQ, nullptr, nullptr, nullptr,
                                     p.PQ, 1024, 128, b & 7, b >> 3, sh, sh + 4096, t);
  else if (b < 2048) scatter_one(p, b - 1024, t);
  else transpose_one(p, b - 2048, t, sh);
}

__global__ __launch_bounds__(256)
void gather_k(GArgs p){
  gather_one(p, blockIdx.y * NN + blockIdx.x * 4 + (threadIdx.x >> 6),
             threadIdx.x & 63);
}

__global__ __launch_bounds__(256)
void msgattn_k(GArgs p){
  __shared__ u16 sh[26112];
  int b = blockIdx.x, t = threadIdx.x;
  if (b < 256)
    gemm_body<false,true,false,u16>(p.S, 512, p.Wtm2, p.mb2, p.deg, nullptr, nullptr,
                                    p.U, 512, 512, b & 1, b >> 1, sh, sh + 4096, t);
  else
    attn_one(p, b - 256, t, sh);
}

__global__ __launch_bounds__(256)
void h1_k(GArgs p){
  __shared__ u16 sh[8192];
  gemm_body<true,false,false,u16>(p.U, 512, p.Wtu1, p.ub1, nullptr, nullptr, nullptr,
                                  p.H1, 512, 512, blockIdx.x, blockIdx.y,
                                  sh, sh + 4096, threadIdx.x);
}
__global__ __launch_bounds__(256)
void h2_k(GArgs p){
  __shared__ u16 sh[8192];
  gemm_body<true,false,false,u16>(p.H1, 512, p.Wtu2, p.ub2, nullptr, nullptr, nullptr,
                                  p.H2, 256, 512, blockIdx.x, blockIdx.y,
                                  sh, sh + 4096, threadIdx.x);
}
__global__ __launch_bounds__(256)
void out_k(GArgs p){
  __shared__ u16 sh[8192];
  gemm_body<false,false,true,float>(p.H2, 256, p.Wtu3, p.ub3, nullptr, p.x1, p.x2,
                                    p.out, 128, 256, blockIdx.x, blockIdx.y,
                                    sh, sh + 4096, threadIdx.x);
}

extern "C" void kernel_launch(void* const* d_in, const int* in_sizes, int n_in,
                              void* d_out, int out_size, void* d_ws, size_t ws_size,
                              hipStream_t stream)
{
  GArgs a;
  a.x1  = (const float*)d_in[0];
  a.ei1 = (const int*)  d_in[1];
  a.x2  = (const float*)d_in[3];
  a.ei2 = (const int*)  d_in[4];
  a.mW1 = (const float*)d_in[6];
  a.mb1 = (const float*)d_in[7];
  a.mW2 = (const float*)d_in[8];
  a.mb2 = (const float*)d_in[9];
  a.uW1 = (const float*)d_in[10];
  a.ub1 = (const float*)d_in[11];
  a.uW2 = (const float*)d_in[12];
  a.ub2 = (const float*)d_in[13];
  a.uW3 = (const float*)d_in[14];
  a.ub3 = (const float*)d_in[15];
  a.out = (float*)d_out;

  char* w = (char*)d_ws;
  auto alloc = [&](size_t b){ char* p = w; w += (b + 255) & ~(size_t)255; return p; };
  a.S    = (u16*)alloc((size_t)2 * NN * 512 * 2);
  a.PQ   = (u16*)alloc((size_t)2 * NN * 1024 * 2);
  a.xb   = (u16*)alloc((size_t)2 * NN * DD * 2);
  a.xt   = (u16*)alloc((size_t)2 * DD * NN * 2);
  a.U    = (u16*)alloc((size_t)2 * NN * 512 * 2);
  a.H1   = (u16*)alloc((size_t)2 * NN * 512 * 2);
  a.H2   = (u16*)alloc((size_t)2 * NN * 256 * 2);
  a.deg  = (int*)alloc((size_t)2 * NN * 4);
  a.offs1 = (int*)alloc((NN + 1) * 4);
  a.offs2 = (int*)alloc((NN + 1) * 4);
  a.cur1  = (int*)alloc(NN * 4);
  a.cur2  = (int*)alloc(NN * 4);
  a.srt1  = (int*)alloc((size_t)EE * 4);
  a.srt2  = (int*)alloc((size_t)EE * 4);
  a.flags = (int*)alloc(520 * 4);
  a.WtPQ = (u16*)alloc(1024 * 128 * 2);
  a.bPQ  = (float*)alloc(1024 * 4);
  a.Wtm2 = (u16*)alloc(256 * 512 * 2);
  a.Wtu1 = (u16*)alloc(512 * 512 * 2);
  a.Wtu2 = (u16*)alloc(256 * 512 * 2);
  a.Wtu3 = (u16*)alloc(128 * 256 * 2);

  // capture-safe occupancy gate for the cooperative path
  int maxB = 0;
  hipError_t qe = hipOccupancyMaxActiveBlocksPerMultiprocessor(&maxB, fused_k, 256, 0);
  if (qe == hipSuccess && maxB >= 2){
    void* kargs[] = { (void*)&a };
    if (hipLaunchCooperativeKernel((const void*)fused_k, dim3(512), dim3(256),
                                   kargs, 0, stream) == hipSuccess)
      return;
  }

  // fallback: R5 pipeline
  hipMemsetAsync(a.deg, 0, (size_t)2 * NN * 4, stream);
  pre_k<<<2692 + 8192 + 1024, 256, 0, stream>>>(a);
  scan_k<<<2, 256, 0, stream>>>(a);
  mid_k<<<2304, 256, 0, stream>>>(a);
  gather_k<<<dim3(2048, 2), 256, 0, stream>>>(a);
  msgattn_k<<<512, 256, 0, stream>>>(a);
  h1_k<<<dim3(4, 128), 256, 0, stream>>>(a);
  h2_k<<<dim3(2, 128), 256, 0, stream>>>(a);
  out_k<<<dim3(1, 128), 256, 0, stream>>>(a);
}

// Round 9
// 284.230 us; speedup vs baseline: 1.0065x; 1.0057x over previous
//
#include <hip/hip_runtime.h>
#include <stdint.h>

// GMNConv R9 = R5 pipeline + BK=128 panel-staged GEMM (4x fewer barrier rounds).
//  pre_k    : weight transpose/cast + x cast (+U x-cols) + edge histogram
//  scan_k   : exclusive prefix scan of deg -> offs/cur
//  mid_k    : PQ = xb@WtPQ^T + bPQ (MFMA)  ||  scatter edges  ||  transpose x
//  gather_k : S[n] = sum relu(P[src]+Q[n])   (no atomics)
//  msgattn_k: msg = S@mW2 + deg*mb2 (MFMA)  ||  block-diag cross-attention
//  h1/h2/out: update MLP GEMMs

typedef unsigned short u16;
typedef __bf16 bf16x8 __attribute__((ext_vector_type(8)));
typedef float f32x4 __attribute__((ext_vector_type(4)));

#define NN 8192
#define DD 128
#define EE 131072
#define GS 128

__device__ __forceinline__ float bf2f(u16 u){
  return __uint_as_float(((uint32_t)u) << 16);
}
__device__ __forceinline__ u16 f2bf(float f){
  uint32_t x = __float_as_uint(f);
  return (u16)((x + 0x7fffu + ((x >> 16) & 1u)) >> 16);
}
__device__ __forceinline__ void gload16(const u16* g, u16* l){
  __builtin_amdgcn_global_load_lds(
      (const __attribute__((address_space(1))) uint32_t*)(uintptr_t)g,
      (__attribute__((address_space(3))) uint32_t*)(uintptr_t)l, 16, 0, 0);
}

struct GArgs {
  const float *x1, *x2;
  const int   *ei1, *ei2;
  const float *mW1, *mb1, *mW2, *mb2;
  const float *uW1, *ub1, *uW2, *ub2, *uW3, *ub3;
  float* out;
  u16 *S, *PQ, *xb, *xt, *U, *H1, *H2;
  int *deg, *offs1, *offs2, *cur1, *cur2, *srt1, *srt2;
  u16 *WtPQ; float* bPQ;
  u16 *Wtm2, *Wtu1, *Wtu2, *Wtu3;
};

// ---- GEMM body, BK=128 staged as 4 panels of m97 geometry ----
// As/Bs: 16384 u16 (32 KB) each = 4 panels [128 rows][32 cols].
// Slot s (16B): panel kk=s>>9, row=(s>>2)&127, colslot=s&3.
// K must be a multiple of 128 (PQ 128, msg/H1/H2 512, out 256).
template<bool RELU, bool DEGBIAS, bool RES, typename OT>
__device__ __forceinline__ void gemm_body(
    const u16* __restrict__ A, int lda,
    const u16* __restrict__ Wt, const float* __restrict__ bias,
    const int* __restrict__ deg,
    const float* __restrict__ res1, const float* __restrict__ res2,
    OT* __restrict__ out, int ldc, int K, int bx, int by,
    u16* As, u16* Bs, int t)
{
  const int brow = by << 7, bcol = bx << 7;
  const int w = t >> 6, lane = t & 63;
  const int rb = (w >> 1) << 6, cb = (w & 1) << 6;
  const int lr = lane & 15, lq = lane >> 4;

  f32x4 acc[4][4];
  #pragma unroll
  for (int i = 0; i < 4; i++)
    #pragma unroll
    for (int j = 0; j < 4; j++) acc[i][j] = (f32x4){0.f, 0.f, 0.f, 0.f};

  // per-thread staging slots: s = i*256 + t, i = 0..7  (2048 slots per matrix)
  int srow[8], scol[8];
  #pragma unroll
  for (int i = 0; i < 8; i++){
    int s = i * 256 + t;
    srow[i] = (s >> 2) & 127;
    scol[i] = ((s >> 9) << 5) + ((s & 3) << 3);   // kk*32 + cs*8
  }

  for (int kb = 0; kb < K; kb += 128){
    #pragma unroll
    for (int i = 0; i < 8; i++){
      int s = i * 256 + t;
      gload16(A  + (size_t)(brow + srow[i]) * lda + kb + scol[i], As + s * 8);
      gload16(Wt + (size_t)(bcol + srow[i]) * K   + kb + scol[i], Bs + s * 8);
    }
    __syncthreads();                    // drains vmcnt -> LDS valid
    #pragma unroll
    for (int kk = 0; kk < 4; kk++){
      const u16* Ap = As + kk * 4096;
      const u16* Bp = Bs + kk * 4096;
      bf16x8 af[4], bfr[4];
      #pragma unroll
      for (int mi = 0; mi < 4; mi++)
        af[mi] = *(const bf16x8*)&Ap[(rb + mi * 16 + lr) * 32 + (lq << 3)];
      #pragma unroll
      for (int ni = 0; ni < 4; ni++)
        bfr[ni] = *(const bf16x8*)&Bp[(cb + ni * 16 + lr) * 32 + (lq << 3)];
      #pragma unroll
      for (int mi = 0; mi < 4; mi++)
        #pragma unroll
        for (int ni = 0; ni < 4; ni++)
          acc[mi][ni] = __builtin_amdgcn_mfma_f32_16x16x32_bf16(af[mi], bfr[ni], acc[mi][ni], 0, 0, 0);
    }
    __syncthreads();                    // protect LDS before next round
  }

  #pragma unroll
  for (int mi = 0; mi < 4; mi++)
    #pragma unroll
    for (int ni = 0; ni < 4; ni++)
      #pragma unroll
      for (int rr = 0; rr < 4; rr++){
        int grow = brow + rb + mi * 16 + lq * 4 + rr;
        int gcol = bcol + cb + ni * 16 + lr;
        float v = acc[mi][ni][rr];
        if (bias) v += DEGBIAS ? (float)deg[grow] * bias[gcol] : bias[gcol];
        if constexpr (RELU) v = fmaxf(v, 0.f);
        if constexpr (RES){
          const float* rp = (grow < NN) ? res1 : res2;
          v += rp[(size_t)(grow & (NN - 1)) * ldc + gcol];
        }
        if constexpr (sizeof(OT) == 2) out[(size_t)grow * ldc + gcol] = (OT)f2bf(v);
        else                           out[(size_t)grow * ldc + gcol] = (OT)v;
      }
}

// ---- phase bodies ----
__device__ __forceinline__ void prep_weights(const GArgs& p, int vb, int t){
  if (vb < 512){                       // WtPQ [1024][128]
    int idx = vb * 256 + t; int c = idx >> 7, k = idx & 127;
    int row = (c < 512) ? k : 128 + k;
    p.WtPQ[idx] = f2bf(p.mW1[(size_t)row * 512 + (c & 511)]);
  } else if (vb < 1024){               // Wtm2 [256][512]
    int idx = (vb - 512) * 256 + t; int c = idx >> 9, k = idx & 511;
    p.Wtm2[idx] = f2bf(p.mW2[(size_t)k * 256 + c]);
  } else if (vb < 2048){               // Wtu1 [512][512]
    int idx = (vb - 1024) * 256 + t; int c = idx >> 9, k = idx & 511;
    p.Wtu1[idx] = f2bf(p.uW1[(size_t)k * 512 + c]);
  } else if (vb < 2560){               // Wtu2 [256][512]
    int idx = (vb - 2048) * 256 + t; int c = idx >> 9, k = idx & 511;
    p.Wtu2[idx] = f2bf(p.uW2[(size_t)k * 256 + c]);
  } else if (vb < 2688){               // Wtu3 [128][256]
    int idx = (vb - 2560) * 256 + t; int c = idx >> 8, k = idx & 255;
    p.Wtu3[idx] = f2bf(p.uW3[(size_t)k * 128 + c]);
  } else {                             // bPQ [1024]
    int idx = (vb - 2688) * 256 + t;
    p.bPQ[idx] = (idx < 512) ? 0.f : p.mb1[idx - 512];
  }
}

__device__ __forceinline__ void cast_x_one(const GArgs& p, int a, int t){
  int side = a >> 12, blk = a & 4095;
  const float* x = side ? p.x2 : p.x1;
  int idx = blk * 256 + t;
  int n = idx >> 7, d = idx & 127;
  u16 v = f2bf(x[idx]);
  p.xb[(size_t)side * NN * DD + idx] = v;
  p.U[((size_t)side * NN + n) * 512 + 384 + d] = v;
}

__device__ __forceinline__ void hist_one(const GArgs& p, int idx, int t){
  int side = idx >> 9, blk = idx & 511;
  const int* ei = side ? p.ei2 : p.ei1;
  int e = blk * 256 + t;
  atomicAdd(&p.deg[side * NN + ei[e]], 1);
}

__device__ __forceinline__ void scatter_one(const GArgs& p, int idx, int t){
  int side = idx >> 9, blk = idx & 511;
  const int* ei = side ? p.ei2 : p.ei1;
  int* cur = side ? p.cur2 : p.cur1;
  int* srt = side ? p.srt2 : p.srt1;
  int e = blk * 256 + t;
  int tgt = ei[e], src = ei[EE + e];
  int pos = atomicAdd(&cur[tgt], 1);
  srt[pos] = src;
}

__device__ __forceinline__ void scan_one(const GArgs& p, int b, int t, int* part){
  const int* d = p.deg + b * NN;
  int* offs = b ? p.offs2 : p.offs1;
  int* cur  = b ? p.cur2  : p.cur1;
  const int base = t * 32;
  int loc[32];
  int s = 0;
  #pragma unroll
  for (int i = 0; i < 32; i++){ loc[i] = s; s += d[base + i]; }
  part[t] = s;
  __syncthreads();
  for (int off = 1; off < 256; off <<= 1){
    int v = (t >= off) ? part[t - off] : 0;
    __syncthreads();
    part[t] += v;
    __syncthreads();
  }
  int pre = (t == 0) ? 0 : part[t - 1];
  #pragma unroll
  for (int i = 0; i < 32; i++){
    int o = pre + loc[i];
    offs[base + i] = o;
    cur[base + i]  = o;
  }
  if (t == 255) offs[NN] = part[255];
}

__device__ __forceinline__ void transpose_one(const GArgs& p, int a, int t, u16* T){
  int side = a >> 7, blk = a & 127;
  const u16* src = p.xb + (size_t)side * NN * DD;
  u16* dst = p.xt + (size_t)side * DD * NN;
  const int n0 = blk * 64;
  #pragma unroll
  for (int i = 0; i < 4; i++){
    int s = i * 256 + t; int r = s >> 4, c8 = (s & 15) << 3;
    *(uint4*)&T[r * 136 + c8] = *(const uint4*)(src + (size_t)(n0 + r) * DD + c8);
  }
  __syncthreads();
  #pragma unroll
  for (int i = 0; i < 8; i++){
    int s = i * 256 + t;
    int d = s >> 4, n4 = (s & 15) << 2;
    uint32_t a0 = T[(n4 + 0) * 136 + d];
    uint32_t a1 = T[(n4 + 1) * 136 + d];
    uint32_t a2 = T[(n4 + 2) * 136 + d];
    uint32_t a3 = T[(n4 + 3) * 136 + d];
    uint2 pk; pk.x = a0 | (a1 << 16); pk.y = a2 | (a3 << 16);
    *(uint2*)(dst + (size_t)d * NN + n0 + n4) = pk;
  }
}

__device__ __forceinline__ void gather_one(const GArgs& p, int nv, int lane){
  int side = nv >> 13, node = nv & (NN - 1);
  const int* offs = side ? p.offs2 : p.offs1;
  const int* srt  = side ? p.srt2  : p.srt1;
  const u16* base = p.PQ + (size_t)side * NN * 1024;
  const int beg = offs[node], end = offs[node + 1];

  uint4 qv = *(const uint4*)(base + (size_t)node * 1024 + 512 + (lane << 3));
  float q[8];
  {
    uint32_t qw[4] = {qv.x, qv.y, qv.z, qv.w};
    #pragma unroll
    for (int i = 0; i < 4; i++){
      q[i * 2]     = bf2f((u16)(qw[i] & 0xffffu));
      q[i * 2 + 1] = bf2f((u16)(qw[i] >> 16));
    }
  }
  float acc[8] = {0.f,0.f,0.f,0.f,0.f,0.f,0.f,0.f};
  int e = beg;
  for (; e + 3 < end; e += 4){
    int sA = srt[e], sB = srt[e+1], sC = srt[e+2], sD = srt[e+3];
    uint4 pA = *(const uint4*)(base + (size_t)sA * 1024 + (lane << 3));
    uint4 pB = *(const uint4*)(base + (size_t)sB * 1024 + (lane << 3));
    uint4 pC = *(const uint4*)(base + (size_t)sC * 1024 + (lane << 3));
    uint4 pD = *(const uint4*)(base + (size_t)sD * 1024 + (lane << 3));
    uint32_t aw[4] = {pA.x, pA.y, pA.z, pA.w};
    uint32_t bw[4] = {pB.x, pB.y, pB.z, pB.w};
    uint32_t cw[4] = {pC.x, pC.y, pC.z, pC.w};
    uint32_t dw[4] = {pD.x, pD.y, pD.z, pD.w};
    #pragma unroll
    for (int i = 0; i < 4; i++){
      acc[i*2]   += fmaxf(bf2f((u16)(aw[i] & 0xffffu)) + q[i*2],   0.f)
                  + fmaxf(bf2f((u16)(bw[i] & 0xffffu)) + q[i*2],   0.f)
                  + fmaxf(bf2f((u16)(cw[i] & 0xffffu)) + q[i*2],   0.f)
                  + fmaxf(bf2f((u16)(dw[i] & 0xffffu)) + q[i*2],   0.f);
      acc[i*2+1] += fmaxf(bf2f((u16)(aw[i] >> 16))     + q[i*2+1], 0.f)
                  + fmaxf(bf2f((u16)(bw[i] >> 16))     + q[i*2+1], 0.f)
                  + fmaxf(bf2f((u16)(cw[i] >> 16))     + q[i*2+1], 0.f)
                  + fmaxf(bf2f((u16)(dw[i] >> 16))     + q[i*2+1], 0.f);
    }
  }
  for (; e < end; e++){
    int sA = srt[e];
    uint4 pA = *(const uint4*)(base + (size_t)sA * 1024 + (lane << 3));
    uint32_t aw[4] = {pA.x, pA.y, pA.z, pA.w};
    #pragma unroll
    for (int i = 0; i < 4; i++){
      acc[i*2]   += fmaxf(bf2f((u16)(aw[i] & 0xffffu)) + q[i*2],   0.f);
      acc[i*2+1] += fmaxf(bf2f((u16)(aw[i] >> 16))     + q[i*2+1], 0.f);
    }
  }
  uint4 pk;
  pk.x = (uint32_t)f2bf(acc[0]) | ((uint32_t)f2bf(acc[1]) << 16);
  pk.y = (uint32_t)f2bf(acc[2]) | ((uint32_t)f2bf(acc[3]) << 16);
  pk.z = (uint32_t)f2bf(acc[4]) | ((uint32_t)f2bf(acc[5]) << 16);
  pk.w = (uint32_t)f2bf(acc[6]) | ((uint32_t)f2bf(acc[7]) << 16);
  *(uint4*)(p.S + ((size_t)side * NN + node) * 512 + (lane << 3)) = pk;
}

// attention block (XaS + XbS LDS staging). sh >= 26112 u16.
__device__ __forceinline__ void attn_one(const GArgs& p, int a, int t, u16* sh){
  const int side = a >> 7;
  const int g = a & 63, h = (a >> 6) & 1;
  const u16* Xa = p.xb + (size_t)side * NN * DD;
  const u16* Xb = p.xb + (size_t)(1 - side) * NN * DD;
  const u16* Xt = p.xt + (size_t)(1 - side) * DD * NN;
  u16* Uside = p.U + (size_t)side * NN * 512;
  u16* XaS = sh;            // 64*136
  u16* XbS = sh + 8704;     // 128*136

  const int w = t >> 6, lane = t & 63;
  const int lr = lane & 15, lq = lane >> 4;

  {
    const u16* sa = Xa + ((size_t)g * GS + h * 64) * DD;
    #pragma unroll
    for (int i = 0; i < 4; i++){
      int s = i * 256 + t; int r = s >> 4, c8 = (s & 15) << 3;
      *(uint4*)&XaS[r * 136 + c8] = *(const uint4*)(sa + (size_t)r * DD + c8);
    }
    const u16* sb = Xb + (size_t)g * GS * DD;
    #pragma unroll
    for (int i = 0; i < 8; i++){
      int s = i * 256 + t; int r = s >> 4, c8 = (s & 15) << 3;
      *(uint4*)&XbS[r * 136 + c8] = *(const uint4*)(sb + (size_t)r * DD + c8);
    }
  }
  __syncthreads();

  f32x4 sc[8];
  #pragma unroll
  for (int ct = 0; ct < 8; ct++) sc[ct] = (f32x4){0.f, 0.f, 0.f, 0.f};
  #pragma unroll
  for (int kb = 0; kb < 4; kb++){
    bf16x8 aa = *(const bf16x8*)&XaS[(w * 16 + lr) * 136 + kb * 32 + (lq << 3)];
    #pragma unroll
    for (int ct = 0; ct < 8; ct++){
      bf16x8 bb = *(const bf16x8*)&XbS[(ct * 16 + lr) * 136 + kb * 32 + (lq << 3)];
      sc[ct] = __builtin_amdgcn_mfma_f32_16x16x32_bf16(aa, bb, sc[ct], 0, 0, 0);
    }
  }
  float inv[4];
  #pragma unroll
  for (int rr = 0; rr < 4; rr++){
    float m = sc[0][rr];
    #pragma unroll
    for (int ct = 1; ct < 8; ct++) m = fmaxf(m, sc[ct][rr]);
    #pragma unroll
    for (int sh_ = 1; sh_ < 16; sh_ <<= 1) m = fmaxf(m, __shfl_xor(m, sh_, 64));
    float s = 0.f;
    #pragma unroll
    for (int ct = 0; ct < 8; ct++){
      float e = __expf(sc[ct][rr] - m);
      sc[ct][rr] = e; s += e;
    }
    #pragma unroll
    for (int sh_ = 1; sh_ < 16; sh_ <<= 1) s += __shfl_xor(s, sh_, 64);
    inv[rr] = 1.f / s;
  }
  #pragma unroll
  for (int ct = 0; ct < 8; ct++)
    #pragma unroll
    for (int rr = 0; rr < 4; rr++)
      XaS[(w * 16 + lq * 4 + rr) * 136 + ct * 16 + lr] = f2bf(sc[ct][rr] * inv[rr]);
  __syncthreads();

  f32x4 o[8];
  #pragma unroll
  for (int ct = 0; ct < 8; ct++) o[ct] = (f32x4){0.f, 0.f, 0.f, 0.f};
  #pragma unroll
  for (int kb = 0; kb < 4; kb++){
    bf16x8 aa = *(const bf16x8*)&XaS[(w * 16 + lr) * 136 + kb * 32 + (lq << 3)];
    #pragma unroll
    for (int ct = 0; ct < 8; ct++){
      bf16x8 bb = *(const bf16x8*)(Xt + (size_t)(ct * 16 + lr) * NN + g * GS + kb * 32 + (lq << 3));
      o[ct] = __builtin_amdgcn_mfma_f32_16x16x32_bf16(aa, bb, o[ct], 0, 0, 0);
    }
  }
  const u16* XaEp = Xa + ((size_t)g * GS + h * 64) * DD;
  #pragma unroll
  for (int ct = 0; ct < 8; ct++)
    #pragma unroll
    for (int rr = 0; rr < 4; rr++){
      int row = w * 16 + lq * 4 + rr, col = ct * 16 + lr;
      float xa = bf2f(XaEp[(size_t)row * DD + col]);
      Uside[((size_t)g * GS + h * 64 + row) * 512 + 256 + col] = f2bf(xa - o[ct][rr]);
    }
}

// ================= kernels =================
__global__ __launch_bounds__(256)
void pre_k(GArgs p){
  int b = blockIdx.x, t = threadIdx.x;
  if (b < 2692) prep_weights(p, b, t);
  else if (b < 2692 + 8192) cast_x_one(p, b - 2692, t);
  else hist_one(p, b - (2692 + 8192), t);
}

__global__ __launch_bounds__(256)
void scan_k(GArgs p){
  __shared__ int part[256];
  scan_one(p, blockIdx.x, threadIdx.x, part);
}

__global__ __launch_bounds__(256)
void mid_k(GArgs p){
  __shared__ u16 sh[32768];          // 64 KB: gemm As|Bs; transpose uses prefix
  int b = blockIdx.x, t = threadIdx.x;
  if (b < 1024)
    gemm_body<false,false,false,u16>(p.xb, 128, p.WtPQ, p.bPQ, nullptr, nullptr, nullptr,
                                     p.PQ, 1024, 128, b & 7, b >> 3,
                                     sh, sh + 16384, t);
  else if (b < 2048) scatter_one(p, b - 1024, t);
  else transpose_one(p, b - 2048, t, sh);
}

__global__ __launch_bounds__(256)
void gather_k(GArgs p){
  gather_one(p, blockIdx.y * NN + blockIdx.x * 4 + (threadIdx.x >> 6),
             threadIdx.x & 63);
}

__global__ __launch_bounds__(256)
void msgattn_k(GArgs p){
  __shared__ u16 sh[32768];
  int b = blockIdx.x, t = threadIdx.x;
  if (b < 256)
    gemm_body<false,true,false,u16>(p.S, 512, p.Wtm2, p.mb2, p.deg, nullptr, nullptr,
                                    p.U, 512, 512, b & 1, b >> 1,
                                    sh, sh + 16384, t);
  else
    attn_one(p, b - 256, t, sh);
}

__global__ __launch_bounds__(256)
void h1_k(GArgs p){
  __shared__ u16 sh[32768];
  gemm_body<true,false,false,u16>(p.U, 512, p.Wtu1, p.ub1, nullptr, nullptr, nullptr,
                                  p.H1, 512, 512, blockIdx.x, blockIdx.y,
                                  sh, sh + 16384, threadIdx.x);
}
__global__ __launch_bounds__(256)
void h2_k(GArgs p){
  __shared__ u16 sh[32768];
  gemm_body<true,false,false,u16>(p.H1, 512, p.Wtu2, p.ub2, nullptr, nullptr, nullptr,
                                  p.H2, 256, 512, blockIdx.x, blockIdx.y,
                                  sh, sh + 16384, threadIdx.x);
}
__global__ __launch_bounds__(256)
void out_k(GArgs p){
  __shared__ u16 sh[32768];
  gemm_body<false,false,true,float>(p.H2, 256, p.Wtu3, p.ub3, nullptr, p.x1, p.x2,
                                    p.out, 128, 256, blockIdx.x, blockIdx.y,
                                    sh, sh + 16384, threadIdx.x);
}

extern "C" void kernel_launch(void* const* d_in, const int* in_sizes, int n_in,
                              void* d_out, int out_size, void* d_ws, size_t ws_size,
                              hipStream_t stream)
{
  GArgs a;
  a.x1  = (const float*)d_in[0];
  a.ei1 = (const int*)  d_in[1];
  a.x2  = (const float*)d_in[3];
  a.ei2 = (const int*)  d_in[4];
  a.mW1 = (const float*)d_in[6];
  a.mb1 = (const float*)d_in[7];
  a.mW2 = (const float*)d_in[8];
  a.mb2 = (const float*)d_in[9];
  a.uW1 = (const float*)d_in[10];
  a.ub1 = (const float*)d_in[11];
  a.uW2 = (const float*)d_in[12];
  a.ub2 = (const float*)d_in[13];
  a.uW3 = (const float*)d_in[14];
  a.ub3 = (const float*)d_in[15];
  a.out = (float*)d_out;

  char* w = (char*)d_ws;
  auto alloc = [&](size_t b){ char* p = w; w += (b + 255) & ~(size_t)255; return p; };
  a.S    = (u16*)alloc((size_t)2 * NN * 512 * 2);
  a.PQ   = (u16*)alloc((size_t)2 * NN * 1024 * 2);
  a.xb   = (u16*)alloc((size_t)2 * NN * DD * 2);
  a.xt   = (u16*)alloc((size_t)2 * DD * NN * 2);
  a.U    = (u16*)alloc((size_t)2 * NN * 512 * 2);
  a.H1   = (u16*)alloc((size_t)2 * NN * 512 * 2);
  a.H2   = (u16*)alloc((size_t)2 * NN * 256 * 2);
  a.deg  = (int*)alloc((size_t)2 * NN * 4);
  a.offs1 = (int*)alloc((NN + 1) * 4);
  a.offs2 = (int*)alloc((NN + 1) * 4);
  a.cur1  = (int*)alloc(NN * 4);
  a.cur2  = (int*)alloc(NN * 4);
  a.srt1  = (int*)alloc((size_t)EE * 4);
  a.srt2  = (int*)alloc((size_t)EE * 4);
  a.WtPQ = (u16*)alloc(1024 * 128 * 2);
  a.bPQ  = (float*)alloc(1024 * 4);
  a.Wtm2 = (u16*)alloc(256 * 512 * 2);
  a.Wtu1 = (u16*)alloc(512 * 512 * 2);
  a.Wtu2 = (u16*)alloc(256 * 512 * 2);
  a.Wtu3 = (u16*)alloc(128 * 256 * 2);

  hipMemsetAsync(a.deg, 0, (size_t)2 * NN * 4, stream);
  pre_k<<<2692 + 8192 + 1024, 256, 0, stream>>>(a);
  scan_k<<<2, 256, 0, stream>>>(a);
  mid_k<<<2304, 256, 0, stream>>>(a);
  gather_k<<<dim3(2048, 2), 256, 0, stream>>>(a);
  msgattn_k<<<512, 256, 0, stream>>>(a);
  h1_k<<<dim3(4, 128), 256, 0, stream>>>(a);
  h2_k<<<dim3(2, 128), 256, 0, stream>>>(a);
  out_k<<<dim3(1, 128), 256, 0, stream>>>(a);
}